// Round 8
// baseline (695.976 us; speedup 1.0000x reference)
//
#include <hip/hip_runtime.h>
#include <stdint.h>

#define NROWS   32768
#define XDIM    1024
#define NCB     8
#define NCODE   1024
#define CDIM    128

#define CHUNK   64
#define NCHUNK  16                // 1024 / 64

// 4 waves * 64 rows = 256 rows/block, 1024 blocks, 2 blocks/CU
#define NTH     256
#define ROWS_PB 256
#define RPW     64

typedef _Float16 h8 __attribute__((ext_vector_type(8)));
typedef float    f4 __attribute__((ext_vector_type(4)));

#define LO_SCALE 2048.0f
#define LO_INV   4.8828125e-4f    // 2^-11

// ws: per (m,chunk) 32 KB blob: [hilo][g<16][k<64][8 halfs], then c2[8192] f32
#define BLOB_BYTES 32768
#define WS_C2   ((size_t)NCB * NCHUNK * BLOB_BYTES)       // 4 MB
#define WS_NEED (WS_C2 + (size_t)NCB * NCODE * 4)

__device__ __forceinline__ void gload_lds16(const void* g, void* l) {
    __builtin_amdgcn_global_load_lds(
        (const __attribute__((address_space(1))) void*)g,
        (__attribute__((address_space(3))) void*)l, 16, 0, 0);
}

// =====================================================================
// Precompute: f16 hi/lo codebooks as 32 KB chunk blobs + fp64 c2.
// blob(m,c) byte (hilo*16384 + g*1024 + k*16 + i*2) = f16 of cb[m][c*64+k][g*8+i]
// =====================================================================
__global__ __launch_bounds__(256)
void precompute_kernel(const float* __restrict__ cb, uint8_t* __restrict__ ws)
{
    float* c2 = (float*)(ws + WS_C2);

    const int idx  = blockIdx.x * 256 + threadIdx.x;  // 131072 = 8192 codes * 16 groups
    const int g    = idx & 15;
    const int code = idx >> 4;          // m*1024 + kk
    const int mm   = code >> 10;
    const int c    = (code & 1023) >> 6;
    const int k    = code & 63;

    const float* src = cb + (size_t)code * CDIM + g * 8;
    float v[8];
    *(f4*)&v[0] = *(const f4*)src;
    *(f4*)&v[4] = *(const f4*)(src + 4);

    _Float16 hh[8], ll[8];
    double s = 0.0;
    #pragma unroll
    for (int i = 0; i < 8; ++i) {
        _Float16 h = (_Float16)v[i];
        float    r = v[i] - (float)h;
        hh[i] = h; ll[i] = (_Float16)(r * LO_SCALE);
        s = fma((double)v[i], (double)v[i], s);
    }
    uint8_t* blob = ws + ((size_t)(mm * NCHUNK + c)) * BLOB_BYTES;
    *(h8*)(blob + g * 1024 + k * 16)         = *(h8*)hh;
    *(h8*)(blob + 16384 + g * 1024 + k * 16) = *(h8*)ll;

    #pragma unroll
    for (int mask = 1; mask <= 8; mask <<= 1)
        s += __shfl_xor(s, mask, 16);
    if (g == 0) c2[code] = (float)s;
}

// =====================================================================
// Fast main kernel: r3 shell (4rs, cap 256, clean memory) +
// immediate-offset inner loop + CHUNK=64 long intervals
// =====================================================================
__global__ __launch_bounds__(NTH, 2)
void quant_fast(const float* __restrict__ x, const float* __restrict__ cb,
                const uint8_t* __restrict__ ws, float* __restrict__ out)
{
    __shared__ __align__(16) _Float16 S[2][2][16][CHUNK][8];  // 64 KB: [buf][hilo][g][k][8]
    __shared__ float c2s[NCODE];                              // 4 KB
    __shared__ float x2s[ROWS_PB];                            // 1 KB
    __shared__ int   idxs[ROWS_PB];                           // 1 KB
    // 70 KB -> 2 blocks/CU

    const float* c2w = (const float*)(ws + WS_C2);

    const int t    = threadIdx.x;
    const int m    = blockIdx.x & 7;     // one m per XCD (proven r3: FETCH 106 MB)
    const int rb   = blockIdx.x >> 3;    // 0..127
    const int row0 = rb * ROWS_PB;

    const int l    = t & 63;
    const int w    = t >> 6;             // wave 0..3, rows w*64..w*64+63
    const int l15  = l & 15;
    const int lh   = l >> 4;             // 0..3

    // ---- staging: pure linear copy, 8 KB per wave per chunk (8 gload_lds16) ----
    auto stage = [&](int c, int buf) {
        const uint8_t* src = ws + ((size_t)(m * NCHUNK + c) << 15) + (w << 13) + (l << 4);
        char* dst = (char*)&S[0][0][0][0][0] + buf * 32768 + (w << 13);
        #pragma unroll
        for (int i = 0; i < 8; ++i)
            gload_lds16(src + (i << 10), dst + (i << 10));
    };

    // ---- c2 via registers ----
    f4 c2v4 = *(const f4*)&c2w[m * NCODE + t * 4];

    // ---- x fragments (4 row-sets) + fused fp64 x2 (r3-proven, bit-exact) ----
    h8 xh[4][4], xl[4][4];
    #pragma unroll
    for (int rs = 0; rs < 4; ++rs) {
        const float* xp = x + (size_t)(row0 + w * RPW + rs * 16 + l15) * XDIM + m * CDIM + lh * 8;
        double s = 0.0;
        #pragma unroll
        for (int ks = 0; ks < 4; ++ks) {
            float v[8];
            *(f4*)&v[0] = *(const f4*)(xp + ks * 32);
            *(f4*)&v[4] = *(const f4*)(xp + ks * 32 + 4);
            #pragma unroll
            for (int i = 0; i < 8; ++i) {
                _Float16 h = (_Float16)v[i];
                float    r = v[i] - (float)h;
                xh[rs][ks][i] = h;
                xl[rs][ks][i] = (_Float16)(r * LO_SCALE);
                s = fma((double)v[i], (double)v[i], s);
            }
        }
        // lanes sharing l15 but different lh hold disjoint 32-dim slices
        s += __shfl_xor(s, 16, 64);
        s += __shfl_xor(s, 32, 64);
        if (lh == 0) x2s[w * RPW + rs * 16 + l15] = (float)s;
    }

    *(f4*)&c2s[t * 4] = c2v4;

    stage(0, 0);   // chunk 0 in flight under nothing; drained below

    asm volatile("s_waitcnt vmcnt(0) lgkmcnt(0)" ::: "memory");
    asm volatile("s_barrier" ::: "memory");

    float x2r[4][4];
    #pragma unroll
    for (int rs = 0; rs < 4; ++rs)
        #pragma unroll
        for (int j = 0; j < 4; ++j)
            x2r[rs][j] = x2s[w * RPW + rs * 16 + lh * 4 + j];

    float mval[4][4];
    int   midx[4][4];
    #pragma unroll
    for (int rs = 0; rs < 4; ++rs)
        #pragma unroll
        for (int j = 0; j < 4; ++j) { mval[rs][j] = 3.0e38f; midx[rs][j] = 0; }

    const char* Sbase = (const char*)&S[0][0][0][0][0] + lh * 1024 + l15 * 16;

    // body: stage c+1 (lands during ~192 MFMAs), compute chunk c, drain, barrier
    auto body = [&](int c, int buf, bool pf) {
        if (pf) stage(c + 1, buf ^ 1);
        #pragma unroll
        for (int cf = 0; cf < 4; ++cf) {
            const int   code = c * CHUNK + cf * 16 + l15;
            const float c2v  = c2s[code];
            f4 aH[4] = {{0,0,0,0},{0,0,0,0},{0,0,0,0},{0,0,0,0}};
            f4 aS[4] = {{0,0,0,0},{0,0,0,0},{0,0,0,0},{0,0,0,0}};
            __builtin_amdgcn_s_setprio(1);
            #pragma unroll
            for (int ks = 0; ks < 4; ++ks) {
                // dim-group g = ks*4+lh, code k = cf*16+l15: all immediates off Sbase
                h8 bh = *(const h8*)(Sbase + buf * 32768 +         ks * 4096 + cf * 256);
                h8 bl = *(const h8*)(Sbase + buf * 32768 + 16384 + ks * 4096 + cf * 256);
                #pragma unroll
                for (int rs = 0; rs < 4; ++rs) {
                    aH[rs] = __builtin_amdgcn_mfma_f32_16x16x32_f16(xh[rs][ks], bh, aH[rs], 0, 0, 0);
                    aS[rs] = __builtin_amdgcn_mfma_f32_16x16x32_f16(xh[rs][ks], bl, aS[rs], 0, 0, 0);
                    aS[rs] = __builtin_amdgcn_mfma_f32_16x16x32_f16(xl[rs][ks], bh, aS[rs], 0, 0, 0);
                }
            }
            __builtin_amdgcn_s_setprio(0);
            #pragma unroll
            for (int rs = 0; rs < 4; ++rs)
                #pragma unroll
                for (int j = 0; j < 4; ++j) {
                    float dot = fmaf(aS[rs][j], LO_INV, aH[rs][j]);
                    float d2  = (x2r[rs][j] + c2v) - 2.0f * dot;  // exact proven formula
                    if (d2 < mval[rs][j]) { mval[rs][j] = d2; midx[rs][j] = code; }
                }
        }
        // c+1's 8 loads were issued ~7000 cycles ago -> drain is free
        asm volatile("s_waitcnt vmcnt(0)" ::: "memory");
        asm volatile("s_barrier" ::: "memory");
    };

    #pragma unroll 1
    for (int cg = 0; cg < NCHUNK; cg += 2) {
        body(cg,     0, true);
        body(cg + 1, 1, cg + 2 < NCHUNK);
    }

    // ---- cross-lane argmin reduce (16 lanes share each row) ----
    #pragma unroll
    for (int mask = 1; mask <= 8; mask <<= 1)
        #pragma unroll
        for (int rs = 0; rs < 4; ++rs)
            #pragma unroll
            for (int j = 0; j < 4; ++j) {
                float ov = __shfl_xor(mval[rs][j], mask, 64);
                int   oi = __shfl_xor(midx[rs][j], mask, 64);
                if (ov < mval[rs][j] || (ov == mval[rs][j] && oi < midx[rs][j])) {
                    mval[rs][j] = ov; midx[rs][j] = oi;
                }
            }
    if (l15 == 0)
        #pragma unroll
        for (int rs = 0; rs < 4; ++rs)
            #pragma unroll
            for (int j = 0; j < 4; ++j)
                idxs[w * RPW + rs * 16 + lh * 4 + j] = midx[rs][j];
    __syncthreads();

    // ---- gather: exact fp32 copy of winning code rows (r3-proven) ----
    #pragma unroll
    for (int pass = 0; pass < 2; ++pass) {
        const int row  = pass * 128 + (t >> 1);
        const int half = (t & 1) * 64;
        const float* src = cb + ((size_t)m * NCODE + idxs[row]) * CDIM + half;
        float*       dst = out + (size_t)(row0 + row) * XDIM + m * CDIM + half;
        #pragma unroll
        for (int i = 0; i < 16; ++i)
            *(f4*)(dst + i * 4) = *(const f4*)(src + i * 4);
    }
}

// =====================================================================
// Fallback (round-1 kernel, known-correct) for small ws_size
// =====================================================================
__global__ __launch_bounds__(512, 4)
void quant_fallback(const float* __restrict__ x, const float* __restrict__ cb,
                    float* __restrict__ out)
{
    __shared__ __align__(16) _Float16 chS[2][32][CDIM];
    __shared__ __align__(16) _Float16 clS[2][32][CDIM];
    __shared__ float  c2s[NCODE];
    __shared__ double x2p[4][128];
    __shared__ float  x2s[128];
    __shared__ int    idxs[128];

    const int t = threadIdx.x, bid = blockIdx.x;
    const int m = bid >> 8, rb = bid & 255, row0 = rb * 128;
    const int l = t & 63, w = t >> 6, l15 = l & 15, lh = l >> 4;
    const int mskr = (l & 7) * 8;

    for (int rep = 0; rep < 2; ++rep) {
        int k = t + rep * 512;
        const float* p = cb + ((size_t)m * NCODE + k) * CDIM;
        double s0 = 0, s1 = 0, s2 = 0, s3 = 0;
        for (int d = 0; d < CDIM; d += 4) {
            double v0 = p[d], v1 = p[d+1], v2 = p[d+2], v3 = p[d+3];
            s0 = fma(v0,v0,s0); s1 = fma(v1,v1,s1); s2 = fma(v2,v2,s2); s3 = fma(v3,v3,s3);
        }
        c2s[k] = (float)((s0+s1)+(s2+s3));
    }
    {
        int row = t >> 2, q = t & 3;
        const float* p = x + (size_t)(row0+row)*XDIM + m*CDIM + q*32;
        double s0 = 0, s1 = 0;
        for (int i = 0; i < 32; i += 2) { double v0=p[i], v1=p[i+1]; s0=fma(v0,v0,s0); s1=fma(v1,v1,s1); }
        x2p[q][row] = s0 + s1;
    }
    h8 xh[4], xl[4];
    {
        const float* xp = x + (size_t)(row0 + w*16 + l15)*XDIM + m*CDIM + lh*8;
        #pragma unroll
        for (int ks = 0; ks < 4; ++ks) {
            float v[8];
            *(f4*)&v[0] = *(const f4*)(xp + ks*32);
            *(f4*)&v[4] = *(const f4*)(xp + ks*32 + 4);
            #pragma unroll
            for (int i = 0; i < 8; ++i) {
                _Float16 h = (_Float16)v[i]; float r = v[i] - (float)h;
                xh[ks][i] = h; xl[ks][i] = (_Float16)(r * LO_SCALE);
            }
        }
    }
    __syncthreads();
    if (t < 128) x2s[t] = (float)((x2p[0][t]+x2p[1][t])+(x2p[2][t]+x2p[3][t]));

    const int kr = t >> 4, db = (t & 15) * 8, ew = db ^ ((kr & 7) * 8);
    auto stage_load = [&](int c, f4& a, f4& b) {
        const float* p = cb + ((size_t)m*NCODE + c*32 + kr)*CDIM + db;
        a = *(const f4*)p; b = *(const f4*)(p + 4);
    };
    auto stage_write = [&](int buf, f4 a, f4 b) {
        float v[8]; *(f4*)&v[0] = a; *(f4*)&v[4] = b;
        _Float16 hh[8], ll[8];
        #pragma unroll
        for (int i = 0; i < 8; ++i) {
            _Float16 h = (_Float16)v[i]; float r = v[i] - (float)h;
            hh[i] = h; ll[i] = (_Float16)(r * LO_SCALE);
        }
        *(h8*)&chS[buf][kr][ew] = *(h8*)hh;
        *(h8*)&clS[buf][kr][ew] = *(h8*)ll;
    };

    f4 pa, pb;
    stage_load(0, pa, pb);
    stage_write(0, pa, pb);
    __syncthreads();

    float x2r[4];
    #pragma unroll
    for (int j = 0; j < 4; ++j) x2r[j] = x2s[w*16 + lh*4 + j];
    float mval[4]; int midx[4];
    #pragma unroll
    for (int j = 0; j < 4; ++j) { mval[j] = 3.0e38f; midx[j] = 0; }

    for (int c = 0; c < 32; ++c) {
        const int cur = c & 1;
        f4 na, nb;
        if (c + 1 < 32) stage_load(c + 1, na, nb);
        #pragma unroll
        for (int cf = 0; cf < 2; ++cf) {
            const int kloc = cf*16 + l15;
            f4 accH = {0,0,0,0}, accS = {0,0,0,0};
            #pragma unroll
            for (int ks = 0; ks < 4; ++ks) {
                const int e = (ks*32 + lh*8) ^ mskr;
                h8 bh = *(const h8*)&chS[cur][kloc][e];
                h8 bl = *(const h8*)&clS[cur][kloc][e];
                accH = __builtin_amdgcn_mfma_f32_16x16x32_f16(xh[ks], bh, accH, 0, 0, 0);
                accS = __builtin_amdgcn_mfma_f32_16x16x32_f16(xh[ks], bl, accS, 0, 0, 0);
                accS = __builtin_amdgcn_mfma_f32_16x16x32_f16(xl[ks], bh, accS, 0, 0, 0);
            }
            const int code = c*32 + kloc;
            const float c2v = c2s[code];
            #pragma unroll
            for (int j = 0; j < 4; ++j) {
                float dot = fmaf(accS[j], LO_INV, accH[j]);
                float d2 = (x2r[j] + c2v) - 2.0f*dot;
                if (d2 < mval[j]) { mval[j] = d2; midx[j] = code; }
            }
        }
        if (c + 1 < 32) stage_write((c + 1) & 1, na, nb);
        __syncthreads();
    }
    #pragma unroll
    for (int mask = 1; mask <= 8; mask <<= 1)
        #pragma unroll
        for (int j = 0; j < 4; ++j) {
            float ov = __shfl_xor(mval[j], mask, 64);
            int   oi = __shfl_xor(midx[j], mask, 64);
            if (ov < mval[j] || (ov == mval[j] && oi < midx[j])) { mval[j] = ov; midx[j] = oi; }
        }
    if (l15 == 0)
        #pragma unroll
        for (int j = 0; j < 4; ++j) idxs[w*16 + lh*4 + j] = midx[j];
    __syncthreads();
    {
        const int row = t >> 2, qd = (t & 3) * 32;
        const float* src = cb + ((size_t)m*NCODE + idxs[row])*CDIM + qd;
        float* dst = out + (size_t)(row0+row)*XDIM + m*CDIM + qd;
        #pragma unroll
        for (int i = 0; i < 8; ++i) *(f4*)(dst + i*4) = *(const f4*)(src + i*4);
    }
}

extern "C" void kernel_launch(void* const* d_in, const int* in_sizes, int n_in,
                              void* d_out, int out_size, void* d_ws, size_t ws_size,
                              hipStream_t stream) {
    const float* x   = (const float*)d_in[0];
    const float* cb  = (const float*)d_in[1];
    float*       out = (float*)d_out;
    if (ws_size >= WS_NEED && d_ws != nullptr) {
        precompute_kernel<<<dim3(512), dim3(256), 0, stream>>>(cb, (uint8_t*)d_ws);
        quant_fast<<<dim3(NCB * (NROWS / ROWS_PB)), dim3(NTH), 0, stream>>>(
            x, cb, (const uint8_t*)d_ws, out);
    } else {
        quant_fallback<<<dim3(2048), dim3(512), 0, stream>>>(x, cb, out);
    }
}

// Round 9
// 298.299 us; speedup vs baseline: 2.3331x; 2.3331x over previous
//
#include <hip/hip_runtime.h>
#include <stdint.h>

#define NROWS   32768
#define XDIM    1024
#define NCB     8
#define NCODE   1024
#define CDIM    128

#define CHUNK   32
#define NCHUNK  (NCODE / CHUNK)   // 32

// 8 waves * 32 rows = 256 rows/block, 1024 blocks, 4 blocks/CU target
#define NTH     512
#define ROWS_PB 256
#define RPW     32

typedef _Float16 h8 __attribute__((ext_vector_type(8)));
typedef float    f4 __attribute__((ext_vector_type(4)));

#define LO_SCALE 2048.0f
#define LO_INV   4.8828125e-4f    // 2^-11

// ---- workspace layout (r2-proven): pre-swizzled flat hi/lo + c2 ----
#define WS_HI   ((size_t)0)
#define WS_LO   ((size_t)NCB * NCODE * CDIM * 2)          // 2 MB
#define WS_C2   ((size_t)2 * NCB * NCODE * CDIM * 2)      // 4 MB
#define WS_NEED (WS_C2 + (size_t)NCB * NCODE * 4)

__device__ __forceinline__ void gload_lds16(const void* g, void* l) {
    __builtin_amdgcn_global_load_lds(
        (const __attribute__((address_space(1))) void*)g,
        (__attribute__((address_space(3))) void*)l, 16, 0, 0);
}

// =====================================================================
// Precompute (r2-verbatim, proven): f16 hi/lo codebooks with the LDS
// XOR swizzle baked into the global layout, plus fp64-accurate c2.
// Layout: flat[(m*1024 + k)*128 + e], e = d ^ ((k&7)*8) (groups of 8 halfs).
// =====================================================================
__global__ __launch_bounds__(256)
void precompute_kernel(const float* __restrict__ cb, uint8_t* __restrict__ ws)
{
    _Float16* hi = (_Float16*)(ws + WS_HI);
    _Float16* lo = (_Float16*)(ws + WS_LO);
    float*    c2 = (float*)(ws + WS_C2);

    const int idx  = blockIdx.x * 256 + threadIdx.x;  // (code, group)
    const int g    = idx & 15;
    const int code = idx >> 4;          // 0..8191 = m*1024 + k
    const int kr   = code & 31;
    const int gs   = g ^ (kr & 7);      // swizzled source group

    const float* src = cb + (size_t)code * CDIM + gs * 8;
    float v[8];
    *(f4*)&v[0] = *(const f4*)src;
    *(f4*)&v[4] = *(const f4*)(src + 4);

    _Float16 hh[8], ll[8];
    double s = 0.0;
    #pragma unroll
    for (int i = 0; i < 8; ++i) {
        _Float16 h = (_Float16)v[i];
        float    r = v[i] - (float)h;
        hh[i] = h; ll[i] = (_Float16)(r * LO_SCALE);
        s = fma((double)v[i], (double)v[i], s);
    }
    const size_t off = (size_t)code * CDIM + g * 8;
    *(h8*)(hi + off) = *(h8*)hh;
    *(h8*)(lo + off) = *(h8*)ll;

    #pragma unroll
    for (int mask = 1; mask <= 8; mask <<= 1)
        s += __shfl_xor(s, mask, 16);
    if (g == 0) c2[code] = (float)s;
}

// =====================================================================
// Fast main kernel: r2 loop (spill-free, VGPR 64) x 8 waves, XCD-pinned
// =====================================================================
__global__ __launch_bounds__(NTH, 4)
void quant_fast(const float* __restrict__ x, const float* __restrict__ cb,
                const uint8_t* __restrict__ ws, float* __restrict__ out)
{
    __shared__ __align__(16) _Float16 chS[2][CHUNK][CDIM];   // 16 KB
    __shared__ __align__(16) _Float16 clS[2][CHUNK][CDIM];   // 16 KB
    __shared__ float  c2s[NCODE];                            // 4 KB
    __shared__ float  x2s[ROWS_PB];                          // 1 KB
    __shared__ int    idxs[ROWS_PB];                         // 1 KB
    // 38 KB -> 4 blocks/CU

    const _Float16* pre_hi = (const _Float16*)(ws + WS_HI);
    const _Float16* pre_lo = (const _Float16*)(ws + WS_LO);
    const float*    c2w    = (const float*)(ws + WS_C2);

    const int t    = threadIdx.x;
    const int m    = blockIdx.x & 7;     // one m per XCD (proven r3: FETCH 106 MB)
    const int rb   = blockIdx.x >> 3;    // 0..127
    const int row0 = rb * ROWS_PB;

    const int l    = t & 63;
    const int w    = t >> 6;             // wave 0..7, rows w*32..w*32+31
    const int l15  = l & 15;
    const int lh   = l >> 4;             // 0..3
    const int mskr = (l & 7) * 8;        // read-side XOR (== (kloc&7)*8 since kloc=cf*16+l15)

    const size_t cbase = (size_t)m * NCODE * CDIM;

    // ---- staging: wave w covers codes [w*4, w*4+4) per dtype; linear dest,
    //      pre-swizzled per-lane source (r2-proven pattern) ----
    auto stage = [&](int c, int buf) {
        const _Float16* gh = pre_hi + cbase + (size_t)(c * CHUNK + w * 4) * CDIM + l * 8;
        const _Float16* gl = pre_lo + cbase + (size_t)(c * CHUNK + w * 4) * CDIM + l * 8;
        gload_lds16(gh, &chS[buf][w * 4][0]);
        gload_lds16(gl, &clS[buf][w * 4][0]);
    };

    stage(0, 0);

    // ---- c2 fill from precomputed ----
    if (t < 256) *(f4*)&c2s[t * 4] = *(const f4*)&c2w[m * NCODE + t * 4];

    // ---- x fragments + fused fp64 x2 (r3-proven, bit-exact) ----
    h8 xh[2][4], xl[2][4];
    #pragma unroll
    for (int rs = 0; rs < 2; ++rs) {
        const float* xp = x + (size_t)(row0 + w * RPW + rs * 16 + l15) * XDIM + m * CDIM + lh * 8;
        double s = 0.0;
        #pragma unroll
        for (int ks = 0; ks < 4; ++ks) {
            float v[8];
            *(f4*)&v[0] = *(const f4*)(xp + ks * 32);
            *(f4*)&v[4] = *(const f4*)(xp + ks * 32 + 4);
            #pragma unroll
            for (int i = 0; i < 8; ++i) {
                _Float16 h = (_Float16)v[i];
                float    r = v[i] - (float)h;
                xh[rs][ks][i] = h;
                xl[rs][ks][i] = (_Float16)(r * LO_SCALE);
                s = fma((double)v[i], (double)v[i], s);
            }
        }
        // lanes sharing l15 but different lh hold disjoint 32-dim slices
        s += __shfl_xor(s, 16, 64);
        s += __shfl_xor(s, 32, 64);
        if (lh == 0) x2s[w * RPW + rs * 16 + l15] = (float)s;
    }

    __syncthreads();   // full drain: chunk 0 staged, x2s/c2s visible

    float x2r[2][4];
    #pragma unroll
    for (int rs = 0; rs < 2; ++rs)
        #pragma unroll
        for (int j = 0; j < 4; ++j)
            x2r[rs][j] = x2s[w * RPW + rs * 16 + lh * 4 + j];

    float mval[2][4];
    int   midx[2][4];
    #pragma unroll
    for (int rs = 0; rs < 2; ++rs)
        #pragma unroll
        for (int j = 0; j < 4; ++j) { mval[rs][j] = 3.0e38f; midx[rs][j] = 0; }

    // ---- main loop: r2-verbatim double buffer ----
    for (int c = 0; c < NCHUNK; ++c) {
        const int cur = c & 1;
        if (c + 1 < NCHUNK) stage(c + 1, cur ^ 1);   // in flight across whole body

        #pragma unroll
        for (int cf = 0; cf < 2; ++cf) {
            const int kloc = cf * 16 + l15;
            f4 accH[2] = {{0,0,0,0},{0,0,0,0}};
            f4 accS[2] = {{0,0,0,0},{0,0,0,0}};
            #pragma unroll
            for (int ks = 0; ks < 4; ++ks) {
                const int e = (ks * 32 + lh * 8) ^ mskr;
                h8 bh = *(const h8*)&chS[cur][kloc][e];
                h8 bl = *(const h8*)&clS[cur][kloc][e];
                accH[0] = __builtin_amdgcn_mfma_f32_16x16x32_f16(xh[0][ks], bh, accH[0], 0, 0, 0);
                accH[1] = __builtin_amdgcn_mfma_f32_16x16x32_f16(xh[1][ks], bh, accH[1], 0, 0, 0);
                accS[0] = __builtin_amdgcn_mfma_f32_16x16x32_f16(xh[0][ks], bl, accS[0], 0, 0, 0);
                accS[0] = __builtin_amdgcn_mfma_f32_16x16x32_f16(xl[0][ks], bh, accS[0], 0, 0, 0);
                accS[1] = __builtin_amdgcn_mfma_f32_16x16x32_f16(xh[1][ks], bl, accS[1], 0, 0, 0);
                accS[1] = __builtin_amdgcn_mfma_f32_16x16x32_f16(xl[1][ks], bh, accS[1], 0, 0, 0);
            }
            const int   code = c * CHUNK + kloc;
            const float c2v  = c2s[code];
            #pragma unroll
            for (int rs = 0; rs < 2; ++rs)
                #pragma unroll
                for (int j = 0; j < 4; ++j) {
                    float dot = fmaf(accS[rs][j], LO_INV, accH[rs][j]);
                    float d2  = (x2r[rs][j] + c2v) - 2.0f * dot;  // exact proven formula
                    if (d2 < mval[rs][j]) { mval[rs][j] = d2; midx[rs][j] = code; }
                }
        }
        __syncthreads();   // drains staged loads; they had the whole body to land
    }

    // ---- cross-lane argmin reduce (16 lanes share each row) ----
    #pragma unroll
    for (int mask = 1; mask <= 8; mask <<= 1)
        #pragma unroll
        for (int rs = 0; rs < 2; ++rs)
            #pragma unroll
            for (int j = 0; j < 4; ++j) {
                float ov = __shfl_xor(mval[rs][j], mask, 64);
                int   oi = __shfl_xor(midx[rs][j], mask, 64);
                if (ov < mval[rs][j] || (ov == mval[rs][j] && oi < midx[rs][j])) {
                    mval[rs][j] = ov; midx[rs][j] = oi;
                }
            }
    if (l15 == 0)
        #pragma unroll
        for (int rs = 0; rs < 2; ++rs)
            #pragma unroll
            for (int j = 0; j < 4; ++j)
                idxs[w * RPW + rs * 16 + lh * 4 + j] = midx[rs][j];
    __syncthreads();

    // ---- gather: exact fp32 copy of winning code rows ----
    {
        const int row  = t >> 1;           // 0..255
        const int half = (t & 1) * 64;
        const float* src = cb + ((size_t)m * NCODE + idxs[row]) * CDIM + half;
        float*       dst = out + (size_t)(row0 + row) * XDIM + m * CDIM + half;
        #pragma unroll
        for (int i = 0; i < 16; ++i)
            *(f4*)(dst + i * 4) = *(const f4*)(src + i * 4);
    }
}

// =====================================================================
// Fallback (round-1 kernel, known-correct) for small ws_size
// =====================================================================
__global__ __launch_bounds__(512, 4)
void quant_fallback(const float* __restrict__ x, const float* __restrict__ cb,
                    float* __restrict__ out)
{
    __shared__ __align__(16) _Float16 chS[2][CHUNK][CDIM];
    __shared__ __align__(16) _Float16 clS[2][CHUNK][CDIM];
    __shared__ float  c2s[NCODE];
    __shared__ double x2p[4][128];
    __shared__ float  x2s[128];
    __shared__ int    idxs[128];

    const int t = threadIdx.x, bid = blockIdx.x;
    const int m = bid >> 8, rb = bid & 255, row0 = rb * 128;
    const int l = t & 63, w = t >> 6, l15 = l & 15, lh = l >> 4;
    const int mskr = (l & 7) * 8;

    for (int rep = 0; rep < 2; ++rep) {
        int k = t + rep * 512;
        const float* p = cb + ((size_t)m * NCODE + k) * CDIM;
        double s0 = 0, s1 = 0, s2 = 0, s3 = 0;
        for (int d = 0; d < CDIM; d += 4) {
            double v0 = p[d], v1 = p[d+1], v2 = p[d+2], v3 = p[d+3];
            s0 = fma(v0,v0,s0); s1 = fma(v1,v1,s1); s2 = fma(v2,v2,s2); s3 = fma(v3,v3,s3);
        }
        c2s[k] = (float)((s0+s1)+(s2+s3));
    }
    {
        int row = t >> 2, q = t & 3;
        const float* p = x + (size_t)(row0+row)*XDIM + m*CDIM + q*32;
        double s0 = 0, s1 = 0;
        for (int i = 0; i < 32; i += 2) { double v0=p[i], v1=p[i+1]; s0=fma(v0,v0,s0); s1=fma(v1,v1,s1); }
        x2p[q][row] = s0 + s1;
    }
    h8 xh[4], xl[4];
    {
        const float* xp = x + (size_t)(row0 + w*16 + l15)*XDIM + m*CDIM + lh*8;
        #pragma unroll
        for (int ks = 0; ks < 4; ++ks) {
            float v[8];
            *(f4*)&v[0] = *(const f4*)(xp + ks*32);
            *(f4*)&v[4] = *(const f4*)(xp + ks*32 + 4);
            #pragma unroll
            for (int i = 0; i < 8; ++i) {
                _Float16 h = (_Float16)v[i]; float r = v[i] - (float)h;
                xh[ks][i] = h; xl[ks][i] = (_Float16)(r * LO_SCALE);
            }
        }
    }
    __syncthreads();
    if (t < 128) x2s[t] = (float)((x2p[0][t]+x2p[1][t])+(x2p[2][t]+x2p[3][t]));

    const int kr = t >> 4, db = (t & 15) * 8, ew = db ^ ((kr & 7) * 8);
    auto stage_load = [&](int c, f4& a, f4& b) {
        const float* p = cb + ((size_t)m*NCODE + c*CHUNK + kr)*CDIM + db;
        a = *(const f4*)p; b = *(const f4*)(p + 4);
    };
    auto stage_write = [&](int buf, f4 a, f4 b) {
        float v[8]; *(f4*)&v[0] = a; *(f4*)&v[4] = b;
        _Float16 hh[8], ll[8];
        #pragma unroll
        for (int i = 0; i < 8; ++i) {
            _Float16 h = (_Float16)v[i]; float r = v[i] - (float)h;
            hh[i] = h; ll[i] = (_Float16)(r * LO_SCALE);
        }
        *(h8*)&chS[buf][kr][ew] = *(h8*)hh;
        *(h8*)&clS[buf][kr][ew] = *(h8*)ll;
    };

    f4 pa, pb;
    stage_load(0, pa, pb);
    stage_write(0, pa, pb);
    __syncthreads();

    float x2r[4];
    #pragma unroll
    for (int j = 0; j < 4; ++j) x2r[j] = x2s[w*16 + lh*4 + j];
    float mval[4]; int midx[4];
    #pragma unroll
    for (int j = 0; j < 4; ++j) { mval[j] = 3.0e38f; midx[j] = 0; }

    for (int c = 0; c < NCHUNK; ++c) {
        const int cur = c & 1;
        f4 na, nb;
        if (c + 1 < NCHUNK) stage_load(c + 1, na, nb);
        #pragma unroll
        for (int cf = 0; cf < 2; ++cf) {
            const int kloc = cf*16 + l15;
            f4 accH = {0,0,0,0}, accS = {0,0,0,0};
            #pragma unroll
            for (int ks = 0; ks < 4; ++ks) {
                const int e = (ks*32 + lh*8) ^ mskr;
                h8 bh = *(const h8*)&chS[cur][kloc][e];
                h8 bl = *(const h8*)&clS[cur][kloc][e];
                accH = __builtin_amdgcn_mfma_f32_16x16x32_f16(xh[ks], bh, accH, 0, 0, 0);
                accS = __builtin_amdgcn_mfma_f32_16x16x32_f16(xh[ks], bl, accS, 0, 0, 0);
                accS = __builtin_amdgcn_mfma_f32_16x16x32_f16(xl[ks], bh, accS, 0, 0, 0);
            }
            const int code = c*CHUNK + kloc;
            const float c2v = c2s[code];
            #pragma unroll
            for (int j = 0; j < 4; ++j) {
                float dot = fmaf(accS[j], LO_INV, accH[j]);
                float d2 = (x2r[j] + c2v) - 2.0f*dot;
                if (d2 < mval[j]) { mval[j] = d2; midx[j] = code; }
            }
        }
        if (c + 1 < NCHUNK) stage_write((c + 1) & 1, na, nb);
        __syncthreads();
    }
    #pragma unroll
    for (int mask = 1; mask <= 8; mask <<= 1)
        #pragma unroll
        for (int j = 0; j < 4; ++j) {
            float ov = __shfl_xor(mval[j], mask, 64);
            int   oi = __shfl_xor(midx[j], mask, 64);
            if (ov < mval[j] || (ov == mval[j] && oi < midx[j])) { mval[j] = ov; midx[j] = oi; }
        }
    if (l15 == 0)
        #pragma unroll
        for (int j = 0; j < 4; ++j) idxs[w*16 + lh*4 + j] = midx[j];
    __syncthreads();
    {
        const int row = t >> 2, qd = (t & 3) * 32;
        const float* src = cb + ((size_t)m*NCODE + idxs[row])*CDIM + qd;
        float* dst = out + (size_t)(row0+row)*XDIM + m*CDIM + qd;
        #pragma unroll
        for (int i = 0; i < 8; ++i) *(f4*)(dst + i*4) = *(const f4*)(src + i*4);
    }
}

extern "C" void kernel_launch(void* const* d_in, const int* in_sizes, int n_in,
                              void* d_out, int out_size, void* d_ws, size_t ws_size,
                              hipStream_t stream) {
    const float* x   = (const float*)d_in[0];
    const float* cb  = (const float*)d_in[1];
    float*       out = (float*)d_out;
    if (ws_size >= WS_NEED && d_ws != nullptr) {
        precompute_kernel<<<dim3(512), dim3(256), 0, stream>>>(cb, (uint8_t*)d_ws);
        quant_fast<<<dim3(NCB * (NROWS / ROWS_PB)), dim3(NTH), 0, stream>>>(
            x, cb, (const uint8_t*)d_ws, out);
    } else {
        quant_fallback<<<dim3(2048), dim3(512), 0, stream>>>(x, cb, out);
    }
}